// Round 14
// baseline (686.222 us; speedup 1.0000x reference)
//
#include <hip/hip_runtime.h>

// 2-layer LSTM (H=32, D=10, T=512), MFMA split-bf16, M-split form.
// ROUND 13 = round-12 (PASSING, 422us) x 2 batch-groups per 512-thread block.
// r10-r12 showed issue-side micro-opts move <2% each: the step is LATENCY-
// bound (LDS round trips, MFMA latency, barrier skew) with 1 wave/SIMD, and
// grid=256 put exactly 1 block/CU so no co-resident wave existed to hide it.
// Fix: fuse TWO independent 16-batch groups (group = tid>>8) into one block
// -> every SIMD hosts 2 data-independent waves that overlap each other's
// stalls. LDS doubled to ~117KB (<160), VGPR 112 < 256 (2-wave cap).
// Math/layout identical to r12: 3-term split MFMA (absmax 2.4e-4),
// shared-reciprocal activation, cross-barrier x prefetch.

#define HH 32
#define DD 10
#define TT 512
#define CH 32              // x timesteps staged per chunk
#define NB 16              // batches per group
#define XPS 776            // x plane stride per batch (shorts)
#define XRS 24             // x row stride per timestep (shorts)
#define RS  40             // h row stride per batch (shorts)
#define ZOFF (NB * XPS)    // zero-row offset (16 shorts)
#define L2E 1.44269504088896340736f

typedef __attribute__((ext_vector_type(4))) float f32x4;
typedef __attribute__((ext_vector_type(8))) short bf16x8;
typedef __attribute__((ext_vector_type(4))) short bf16x4;
typedef __attribute__((ext_vector_type(2))) float f2;

__device__ __forceinline__ short bfhi(float x, float& rem) {
    unsigned u = __float_as_uint(x);
    unsigned short h = (unsigned short)((u + 0x8000u) >> 16);
    rem = x - __uint_as_float(((unsigned)h) << 16);   // exact residual
    return (short)h;
}
__device__ __forceinline__ short bfrd(float x) {
    return (short)(unsigned short)((__float_as_uint(x) + 0x8000u) >> 16);
}
__device__ __forceinline__ f32x4 mfma16(const bf16x8 a, const bf16x8 b, f32x4 c) {
    return __builtin_amdgcn_mfma_f32_16x16x32_bf16(a, b, c, 0, 0, 0);
}

__global__ __launch_bounds__(512, 2) void lstm2_r13(
    const float* __restrict__ x,
    const float* __restrict__ Wih0, const float* __restrict__ Whh0,
    const float* __restrict__ bih0, const float* __restrict__ bhh0,
    const float* __restrict__ Wih1, const float* __restrict__ Whh1,
    const float* __restrict__ bih1, const float* __restrict__ bhh1,
    const float* __restrict__ Wfc,  const float* __restrict__ bfc,
    float* __restrict__ out)
{
    __shared__ __align__(16) short xh[2][NB * XPS + 16]; // 2 x 24.9 KB
    __shared__ __align__(16) short xl[2][NB * XPS + 16]; // 2 x 24.9 KB
    __shared__ __align__(16) short hb[2][4][2][NB][RS];  // 2 x 10 KB

    const int tid  = threadIdx.x;    // 0..511
    const int grp  = tid >> 8;       // independent batch-group 0/1
    const int ltid = tid & 255;      // within-group thread id
    const int wid  = ltid >> 6;      // 0,1 = L1 halves; 2,3 = L2 halves
    const bool isL2 = wid >= 2;
    const int hf   = wid & 1;        // unit half: 0 -> units 0-15, 1 -> 16-31
    const int lane = ltid & 63;
    const int b    = lane & 15;      // batch col (B/D) / row-local (A)
    const int g4   = lane >> 4;      // k-slot group
    const int b0   = blockIdx.x * (2 * NB) + grp * NB;

    for (int i = tid; i < (int)(sizeof(hb) / 4); i += 512) ((int*)hb)[i] = 0;
    if (ltid < 16) { xh[grp][ZOFF + ltid] = 0; xl[grp][ZOFF + ltid] = 0; }

    // ---- bias in registers: rows 32j + 16hf + 4g4 + (0..3) ----
    f32x4 bias[4];
    #pragma unroll
    for (int j = 0; j < 4; ++j) {
        const int rb = 32 * j + 16 * hf + 4 * g4;
        const float sc = L2E * ((j == 2) ? 2.0f : 1.0f);
        f32x4 bi, bh_;
        if (!isL2) { bi = *(const f32x4*)&bih0[rb]; bh_ = *(const f32x4*)&bhh0[rb]; }
        else       { bi = *(const f32x4*)&bih1[rb]; bh_ = *(const f32x4*)&bhh1[rb]; }
        bias[j] = (bi + bh_) * sc;
    }

    // ---- A-fragments, hi/lo split; this wave's M-tiles m = 2j + hf ----
    bf16x8 Ah[4][2], Al[4][2];
    #pragma unroll
    for (int j = 0; j < 4; ++j) {
        const int m = 2 * j + hf;
        const int row = 16 * m + b;
        const float sc = L2E * ((j == 2) ? 2.0f : 1.0f);
        #pragma unroll
        for (int kt = 0; kt < 2; ++kt) {
            bf16x8 hi, lo;
            #pragma unroll
            for (int e = 0; e < 8; ++e) {
                const int k = 8 * g4 + e;
                float w;
                if (!isL2) w = (kt == 0) ? Whh0[row * HH + k]
                                         : ((k < DD) ? Wih0[row * DD + k] : 0.0f);
                else       w = (kt == 0) ? Wih1[row * HH + k]
                                         : Whh1[row * HH + k];
                w *= sc;
                float rem;
                hi[e] = bfhi(w, rem);
                lo[e] = bfrd(rem);
            }
            Ah[j][kt] = hi;
            Al[j][kt] = lo;
        }
    }
    // pin fragments into VGPRs
    #pragma unroll
    for (int j = 0; j < 4; ++j) {
        asm volatile("" : "+v"(Ah[j][0]), "+v"(Ah[j][1]),
                          "+v"(Al[j][0]), "+v"(Al[j][1]));
    }

    float cst[4] = {0.f, 0.f, 0.f, 0.f};   // cell state, units 16hf+4g4+r
    bf16x8 pXh, pXl;                        // L1 x-frag prefetch registers
    __syncthreads();

#define STEP(KK, PR, DOL1, DOL2, XIN, XOUT) do {                               \
    const bool act_ = isL2 ? (DOL2) : (DOL1);                                  \
    if (act_) {                                                                \
        bf16x8 Bh0, Bl0, Bh1, Bl1;                                             \
        if (!isL2) {                                                           \
            if (XIN) { Bh1 = pXh; Bl1 = pXl; }                                 \
            else {                                                             \
                const int tc0_ = (KK) & (CH - 1);                              \
                const int xo_ = (g4 < 2) ? (b * XPS + tc0_ * XRS + 8 * g4)     \
                                         : ZOFF;                               \
                Bh1 = *(const bf16x8*)&xh[grp][xo_];                           \
                Bl1 = *(const bf16x8*)&xl[grp][xo_];                           \
            }                                                                  \
        } else {                                                               \
            Bh1 = *(const bf16x8*)&hb[grp][2][PR][b][8 * g4];                  \
            Bl1 = *(const bf16x8*)&hb[grp][3][PR][b][8 * g4];                  \
        }                                                                      \
        Bh0 = *(const bf16x8*)&hb[grp][0][(PR) ^ 1][b][8 * g4];                \
        Bl0 = *(const bf16x8*)&hb[grp][1][(PR) ^ 1][b][8 * g4];                \
        f32x4 acc[4];                                                          \
        _Pragma("unroll")                                                      \
        for (int j = 0; j < 4; ++j) {                                          \
            f32x4 aB = {0.f, 0.f, 0.f, 0.f};      /* barrier-independent */    \
            aB = mfma16(Ah[j][1], Bh1, aB);                                    \
            aB = mfma16(Al[j][1], Bh1, aB);                                    \
            aB = mfma16(Ah[j][1], Bl1, aB);                                    \
            f32x4 aA = bias[j];                    /* h1-dependent */          \
            aA = mfma16(Ah[j][0], Bh0, aA);                                    \
            aA = mfma16(Al[j][0], Bh0, aA);                                    \
            aA = mfma16(Ah[j][0], Bl0, aA);                                    \
            acc[j] = aA + aB;                                                  \
        }                                                                      \
        short hh_[4], hl_[4];                                                  \
        _Pragma("unroll")                                                      \
        for (int r = 0; r < 4; ++r) {                                          \
            const float e1 = exp2f(-acc[0][r]);   /* i */                      \
            const float e2 = exp2f(-acc[1][r]);   /* f */                      \
            const float e3 = exp2f(-acc[2][r]);   /* g (pre-scaled 2*L2E) */   \
            const float e4 = exp2f(-acc[3][r]);   /* o */                      \
            const float d1 = 1.0f + e1, d2 = 1.0f + e2;                        \
            const float d3 = 1.0f + e3, d4 = 1.0f + e4;                        \
            const float p12  = d1 * d2;                                        \
            const float p123 = p12 * d3;                                       \
            const float s34  = d3 * d4;                                        \
            const float s234 = d2 * s34;                                       \
            const float t3   = p12 * d4;                                       \
            const float R  = __builtin_amdgcn_rcpf(p123 * d4);                 \
            const float si = R * s234;            /* sigmoid(i) */             \
            const float sf = (R * d1) * s34;      /* sigmoid(f) */             \
            const float so = R * p123;            /* sigmoid(o) */             \
            const float tg = fmaf(2.0f * R, t3, -1.0f);   /* tanh(g) */        \
            const float cn = fmaf(sf, cst[r], si * tg);                        \
            cst[r] = cn;                                                       \
            const float ec = exp2f(-2.0f * L2E * cn);                          \
            const float tc = fmaf(2.0f,                                        \
                __builtin_amdgcn_rcpf(1.0f + ec), -1.0f);     /* tanh(c) */    \
            const float h_ = so * tc;                                          \
            float rem_;                                                        \
            hh_[r] = bfhi(h_, rem_);                                           \
            hl_[r] = bfrd(rem_);                                               \
        }                                                                      \
        const int arr_ = isL2 ? 2 : 0;                                         \
        const int wp_  = isL2 ? ((PR) ^ 1) : (PR);                             \
        *(bf16x4*)&hb[grp][arr_][wp_][b][16 * hf + 4 * g4]     =               \
            bf16x4{hh_[0], hh_[1], hh_[2], hh_[3]};                            \
        *(bf16x4*)&hb[grp][arr_ + 1][wp_][b][16 * hf + 4 * g4] =               \
            bf16x4{hl_[0], hl_[1], hl_[2], hl_[3]};                            \
    }                                                                          \
    if (!isL2 && (XOUT)) {          /* cross-barrier x prefetch for KK+1 */    \
        const int tcn_ = ((KK) + 1) & (CH - 1);                                \
        const int xo_ = (g4 < 2) ? (b * XPS + tcn_ * XRS + 8 * g4) : ZOFF;     \
        pXh = *(const bf16x8*)&xh[grp][xo_];                                   \
        pXl = *(const bf16x8*)&xl[grp][xo_];                                   \
    }                                                                          \
    __syncthreads();                                                           \
} while (0)

    for (int ch = 0; ch < TT / CH; ++ch) {
        const int k0 = ch * CH;
        // ---- stage + pre-split x chunk (coalesced; per group) ----
        #pragma unroll
        for (int p = 0; p < (CH * NB) / 256; ++p) {
            const int idx = ltid + 256 * p;
            const int t = idx & (CH - 1), bb = idx >> 5;
            const f2* sp = (const f2*)(x + (size_t)(b0 + bb) * (TT * DD)
                                         + (size_t)(k0 + t) * DD);
            f2 v0 = sp[0], v1 = sp[1], v2 = sp[2], v3 = sp[3], v4 = sp[4];
            const float av[10] = {v0.x, v0.y, v1.x, v1.y, v2.x,
                                  v2.y, v3.x, v3.y, v4.x, v4.y};
            short th[16], tl[16];
            #pragma unroll
            for (int d = 0; d < DD; ++d) {
                float rem;
                th[d] = bfhi(av[d], rem);
                tl[d] = bfrd(rem);
            }
            #pragma unroll
            for (int d = DD; d < 16; ++d) { th[d] = 0; tl[d] = 0; }
            short* ph = &xh[grp][bb * XPS + t * XRS];
            short* pl = &xl[grp][bb * XPS + t * XRS];
            *(bf16x8*)(ph)     = bf16x8{th[0],th[1],th[2],th[3],th[4],th[5],th[6],th[7]};
            *(bf16x8*)(ph + 8) = bf16x8{th[8],th[9],th[10],th[11],th[12],th[13],th[14],th[15]};
            *(bf16x8*)(pl)     = bf16x8{tl[0],tl[1],tl[2],tl[3],tl[4],tl[5],tl[6],tl[7]};
            *(bf16x8*)(pl + 8) = bf16x8{tl[8],tl[9],tl[10],tl[11],tl[12],tl[13],tl[14],tl[15]};
        }
        __syncthreads();

        for (int t2 = 0; t2 < CH; t2 += 2) {
            const int kk = k0 + t2;
            // re-pin A-frags once per step pair (costless if VGPR-resident)
            #pragma unroll
            for (int j = 0; j < 4; ++j) {
                asm volatile("" : "+v"(Ah[j][0]), "+v"(Ah[j][1]),
                                  "+v"(Al[j][0]), "+v"(Al[j][1]));
            }
            const bool xin0  = (t2 != 0);
            const bool xoutB = (t2 + 2 < CH);
            STEP(kk,     0, true, kk > 0, xin0, true);
            STEP(kk + 1, 1, true, true,   true, xoutB);
        }
    }
    // drain: L2 computes timestep 511 at wavefront-iter 512 (parity 0)
    STEP(TT, 0, false, true, false, false);
#undef STEP

    // ---- final FC on h2(511): parity 1 -> hb[grp][2/3][1] ----
    if (ltid < NB) {
        float v = bfc[0];
        #pragma unroll
        for (int u = 0; u < HH; ++u) {
            const unsigned hi = (unsigned short)hb[grp][2][1][ltid][u];
            const unsigned lo = (unsigned short)hb[grp][3][1][ltid][u];
            const float h = __uint_as_float(hi << 16) + __uint_as_float(lo << 16);
            v = fmaf(h, Wfc[u], v);
        }
        out[b0 + ltid] = v;
    }
}

extern "C" void kernel_launch(void* const* d_in, const int* in_sizes, int n_in,
                              void* d_out, int out_size, void* d_ws, size_t ws_size,
                              hipStream_t stream) {
    const float* x    = (const float*)d_in[0];
    const float* Wih0 = (const float*)d_in[1];
    const float* Whh0 = (const float*)d_in[2];
    const float* bih0 = (const float*)d_in[3];
    const float* bhh0 = (const float*)d_in[4];
    const float* Wih1 = (const float*)d_in[5];
    const float* Whh1 = (const float*)d_in[6];
    const float* bih1 = (const float*)d_in[7];
    const float* bhh1 = (const float*)d_in[8];
    const float* Wfc  = (const float*)d_in[9];
    const float* bfc  = (const float*)d_in[10];
    float* out = (float*)d_out;

    const int B = in_sizes[0] / (TT * DD);   // 4096
    dim3 grid(B / (2 * NB)), block(512);     // 128 blocks x 8 waves (2 groups)
    hipLaunchKernelGGL(lstm2_r13, grid, block, 0, stream,
                       x, Wih0, Whh0, bih0, bhh0,
                       Wih1, Whh1, bih1, bhh1, Wfc, bfc, out);
}

// Round 15
// 515.145 us; speedup vs baseline: 1.3321x; 1.3321x over previous
//
#include <hip/hip_runtime.h>

// 2-layer LSTM (H=32, D=10, T=512), MFMA split-bf16, K-SPLIT 8-wave form.
// r13 lesson: grid=128 left half the CUs idle; per-CU 2-wave throughput was
// 1.29x -> TLP helps but must keep grid=256. Only route: split each (layer,
// half) wave into s=0 (h1-side MFMAs + bias) and s=1 (x/h2-side MFMAs).
// fp32 partials exchanged via LDS; activation split 2 cells/wave (s=0:r01,
// s=1:r23) halving the per-wave transcendental chain. 2 barriers/step.
// 8 waves/block x 256 blocks = 2 waves/SIMD on ALL CUs.
// 3-term split (AhBh+AlBh+AhBl) unchanged -> absmax 2.4e-4 expected.

#define HH 32
#define DD 10
#define TT 512
#define CH 32              // x timesteps staged per chunk
#define NB 16              // batches per block
#define XPS 776            // x plane stride per batch (shorts)
#define XRS 24             // x row stride per timestep (shorts)
#define RS  40             // h row stride per batch (shorts)
#define ZOFF (NB * XPS)    // zero-row offset (16 shorts)
#define PEXS 10            // pex lane stride (floats; pad for banks)
#define L2E 1.44269504088896340736f

typedef __attribute__((ext_vector_type(4))) float f32x4;
typedef __attribute__((ext_vector_type(8))) short bf16x8;
typedef __attribute__((ext_vector_type(2))) float f2;

__device__ __forceinline__ short bfhi(float x, float& rem) {
    unsigned u = __float_as_uint(x);
    unsigned short h = (unsigned short)((u + 0x8000u) >> 16);
    rem = x - __uint_as_float(((unsigned)h) << 16);   // exact residual
    return (short)h;
}
__device__ __forceinline__ short bfrd(float x) {
    return (short)(unsigned short)((__float_as_uint(x) + 0x8000u) >> 16);
}
__device__ __forceinline__ f32x4 mfma16(const bf16x8 a, const bf16x8 b, f32x4 c) {
    return __builtin_amdgcn_mfma_f32_16x16x32_bf16(a, b, c, 0, 0, 0);
}

__global__ __launch_bounds__(512, 2) void lstm2_ks8(
    const float* __restrict__ x,
    const float* __restrict__ Wih0, const float* __restrict__ Whh0,
    const float* __restrict__ bih0, const float* __restrict__ bhh0,
    const float* __restrict__ Wih1, const float* __restrict__ Whh1,
    const float* __restrict__ bih1, const float* __restrict__ bhh1,
    const float* __restrict__ Wfc,  const float* __restrict__ bfc,
    float* __restrict__ out)
{
    __shared__ __align__(16) short xh[NB * XPS + 16]; // 24.9 KB  x hi + zero row
    __shared__ __align__(16) short xl[NB * XPS + 16]; // 24.9 KB  x lo + zero row
    __shared__ __align__(16) short hb[4][2][NB][RS];  // 10 KB: h1h,h1l,h2h,h2l
    __shared__ __align__(16) float pex[8][64][PEXS];  // 20 KB partial exchange

    const int tid  = threadIdx.x;    // 0..511
    const int wid  = tid >> 6;       // wave id 0..7
    const int s    = wid & 1;        // k-split: 0 = h1-side, 1 = x/h2-side
    const int hf   = (wid >> 1) & 1; // unit half: 0 -> units 0-15, 1 -> 16-31
    const bool isL2 = wid >= 4;
    const int lane = tid & 63;
    const int b    = lane & 15;      // batch col (B/D) / row-local (A)
    const int g4   = lane >> 4;      // k-slot group
    const int b0   = blockIdx.x * NB;

    for (int i = tid; i < (int)(sizeof(hb) / 4); i += 512) ((int*)hb)[i] = 0;
    if (tid < 16) { xh[ZOFF + tid] = 0; xl[ZOFF + tid] = 0; }

    // ---- bias in registers (used by s==0 waves): rows 32j + 16hf + 4g4 ----
    f32x4 bias[4];
    #pragma unroll
    for (int j = 0; j < 4; ++j) {
        const int rb = 32 * j + 16 * hf + 4 * g4;
        const float sc = L2E * ((j == 2) ? 2.0f : 1.0f);
        f32x4 bi, bh_;
        if (!isL2) { bi = *(const f32x4*)&bih0[rb]; bh_ = *(const f32x4*)&bhh0[rb]; }
        else       { bi = *(const f32x4*)&bih1[rb]; bh_ = *(const f32x4*)&bhh1[rb]; }
        bias[j] = (bi + bh_) * sc;
    }

    // ---- A-fragments for THIS wave's k-tile (kt = s), hi/lo split ----
    // row = 16(2j+hf) + b, k = 8*g4 + e.
    // L1: s0 = Whh0 (h1), s1 = Wih0 (x, k<10 else 0).
    // L2: s0 = Wih1 (h1), s1 = Whh1 (h2).
    bf16x8 Ah[4], Al[4];
    #pragma unroll
    for (int j = 0; j < 4; ++j) {
        const int row = 16 * (2 * j + hf) + b;
        const float sc = L2E * ((j == 2) ? 2.0f : 1.0f);
        bf16x8 hi, lo;
        #pragma unroll
        for (int e = 0; e < 8; ++e) {
            const int k = 8 * g4 + e;
            float w;
            if (!isL2) w = (s == 0) ? Whh0[row * HH + k]
                                    : ((k < DD) ? Wih0[row * DD + k] : 0.0f);
            else       w = (s == 0) ? Wih1[row * HH + k]
                                    : Whh1[row * HH + k];
            w *= sc;
            float rem;
            hi[e] = bfhi(w, rem);
            lo[e] = bfrd(rem);
        }
        Ah[j] = hi;
        Al[j] = lo;
    }
    #pragma unroll
    for (int j = 0; j < 4; ++j) asm volatile("" : "+v"(Ah[j]), "+v"(Al[j]));

    float cst[2] = {0.f, 0.f};       // cell state, units 16hf+4g4+2s+{0,1}
    __syncthreads();

#define STEPX(KK, PR, DOL1, DOL2) do {                                         \
    const bool act_ = isL2 ? (DOL2) : (DOL1);                                  \
    f32x4 acc[4];                                                              \
    if (act_) {                                                                \
        bf16x8 Bh, Bl;                                                         \
        if (s == 0) {               /* h1(k-1) side (both layers) */           \
            Bh = *(const bf16x8*)&hb[0][(PR) ^ 1][b][8 * g4];                  \
            Bl = *(const bf16x8*)&hb[1][(PR) ^ 1][b][8 * g4];                  \
        } else if (isL2) {          /* h2(k-2) side */                         \
            Bh = *(const bf16x8*)&hb[2][PR][b][8 * g4];                        \
            Bl = *(const bf16x8*)&hb[3][PR][b][8 * g4];                        \
        } else {                    /* x side (chunk-static) */                \
            const int tc_ = (KK) & (CH - 1);                                   \
            const int xo_ = (g4 < 2) ? (b * XPS + tc_ * XRS + 8 * g4) : ZOFF;  \
            Bh = *(const bf16x8*)&xh[xo_];                                     \
            Bl = *(const bf16x8*)&xl[xo_];                                     \
        }                                                                      \
        _Pragma("unroll")                                                      \
        for (int j = 0; j < 4; ++j) {                                          \
            f32x4 a_;                                                          \
            if (s == 0) a_ = bias[j];                                          \
            else { a_[0] = 0.f; a_[1] = 0.f; a_[2] = 0.f; a_[3] = 0.f; }       \
            a_ = mfma16(Ah[j], Bh, a_);                                        \
            a_ = mfma16(Al[j], Bh, a_);                                        \
            a_ = mfma16(Ah[j], Bl, a_);                                        \
            acc[j] = a_;                                                       \
        }                                                                      \
        float* pw = &pex[wid][lane][0];                                        \
        _Pragma("unroll")                                                      \
        for (int j = 0; j < 4; ++j) {      /* send partner's r-pair */         \
            f2 t_;                                                             \
            t_.x = acc[j][2 - 2 * s];                                          \
            t_.y = acc[j][3 - 2 * s];                                          \
            *(f2*)(pw + 2 * j) = t_;                                           \
        }                                                                      \
    }                                                                          \
    __syncthreads();                                                           \
    if (act_) {                                                                \
        const float* prd = &pex[wid ^ 1][lane][0];                             \
        float sum[4][2];                                                       \
        _Pragma("unroll")                                                      \
        for (int j = 0; j < 4; ++j) {                                          \
            f2 t_ = *(const f2*)(prd + 2 * j);                                 \
            sum[j][0] = acc[j][2 * s]     + t_.x;                              \
            sum[j][1] = acc[j][2 * s + 1] + t_.y;                              \
        }                                                                      \
        short hh_[2], hl_[2];                                                  \
        _Pragma("unroll")                                                      \
        for (int cc = 0; cc < 2; ++cc) {                                       \
            const float e1 = exp2f(-sum[0][cc]);   /* i */                     \
            const float e2 = exp2f(-sum[1][cc]);   /* f */                     \
            const float e3 = exp2f(-sum[2][cc]);   /* g (pre-scaled 2L2E) */   \
            const float e4 = exp2f(-sum[3][cc]);   /* o */                     \
            const float d1 = 1.0f + e1, d2 = 1.0f + e2;                        \
            const float d3 = 1.0f + e3, d4 = 1.0f + e4;                        \
            const float p12  = d1 * d2;                                        \
            const float p123 = p12 * d3;                                       \
            const float s34  = d3 * d4;                                        \
            const float s234 = d2 * s34;                                       \
            const float t3   = p12 * d4;                                       \
            const float R  = __builtin_amdgcn_rcpf(p123 * d4);                 \
            const float si = R * s234;                                         \
            const float sf = (R * d1) * s34;                                   \
            const float so = R * p123;                                         \
            const float tg = fmaf(2.0f * R, t3, -1.0f);                        \
            const float cn = fmaf(sf, cst[cc], si * tg);                       \
            cst[cc] = cn;                                                      \
            const float ec = exp2f(-2.0f * L2E * cn);                          \
            const float tc = fmaf(2.0f,                                        \
                __builtin_amdgcn_rcpf(1.0f + ec), -1.0f);                      \
            const float h_ = so * tc;                                          \
            float rem_;                                                        \
            hh_[cc] = bfhi(h_, rem_);                                          \
            hl_[cc] = bfrd(rem_);                                              \
        }                                                                      \
        const int arr_ = isL2 ? 2 : 0;                                         \
        const int wp_  = isL2 ? ((PR) ^ 1) : (PR);                             \
        const int ub_  = 16 * hf + 4 * g4 + 2 * s;                             \
        const unsigned ph_ = (unsigned short)hh_[0]                            \
                           | ((unsigned)(unsigned short)hh_[1] << 16);         \
        const unsigned pl_ = (unsigned short)hl_[0]                            \
                           | ((unsigned)(unsigned short)hl_[1] << 16);         \
        *(unsigned*)&hb[arr_][wp_][b][ub_]     = ph_;                          \
        *(unsigned*)&hb[arr_ + 1][wp_][b][ub_] = pl_;                          \
    }                                                                          \
    __syncthreads();                                                           \
} while (0)

    for (int ch = 0; ch < TT / CH; ++ch) {
        const int k0 = ch * CH;
        // ---- stage + pre-split x chunk (512 threads, 1 item each) ----
        {
            const int t = tid & (CH - 1), bb = tid >> 5;
            const f2* sp = (const f2*)(x + (size_t)(b0 + bb) * (TT * DD)
                                         + (size_t)(k0 + t) * DD);
            f2 v0 = sp[0], v1 = sp[1], v2 = sp[2], v3 = sp[3], v4 = sp[4];
            const float av[10] = {v0.x, v0.y, v1.x, v1.y, v2.x,
                                  v2.y, v3.x, v3.y, v4.x, v4.y};
            short th[16], tl[16];
            #pragma unroll
            for (int d = 0; d < DD; ++d) {
                float rem;
                th[d] = bfhi(av[d], rem);
                tl[d] = bfrd(rem);
            }
            #pragma unroll
            for (int d = DD; d < 16; ++d) { th[d] = 0; tl[d] = 0; }
            short* ph = &xh[bb * XPS + t * XRS];
            short* pl = &xl[bb * XPS + t * XRS];
            *(bf16x8*)(ph)     = bf16x8{th[0],th[1],th[2],th[3],th[4],th[5],th[6],th[7]};
            *(bf16x8*)(ph + 8) = bf16x8{th[8],th[9],th[10],th[11],th[12],th[13],th[14],th[15]};
            *(bf16x8*)(pl)     = bf16x8{tl[0],tl[1],tl[2],tl[3],tl[4],tl[5],tl[6],tl[7]};
            *(bf16x8*)(pl + 8) = bf16x8{tl[8],tl[9],tl[10],tl[11],tl[12],tl[13],tl[14],tl[15]};
        }
        __syncthreads();

        for (int t2 = 0; t2 < CH; t2 += 2) {
            const int kk = k0 + t2;
            #pragma unroll
            for (int j = 0; j < 4; ++j)
                asm volatile("" : "+v"(Ah[j]), "+v"(Al[j]));
            STEPX(kk,     0, true, kk > 0);
            STEPX(kk + 1, 1, true, true);
        }
    }
    // drain: L2 computes timestep 511 at wavefront-iter 512 (parity 0)
    STEPX(TT, 0, false, true);
#undef STEPX

    // ---- final FC on h2(511): parity 1 -> hb[2/3][1] ----
    if (tid < NB) {
        float v = bfc[0];
        #pragma unroll
        for (int u = 0; u < HH; ++u) {
            const unsigned hi = (unsigned short)hb[2][1][tid][u];
            const unsigned lo = (unsigned short)hb[3][1][tid][u];
            const float h = __uint_as_float(hi << 16) + __uint_as_float(lo << 16);
            v = fmaf(h, Wfc[u], v);
        }
        out[b0 + tid] = v;
    }
}

extern "C" void kernel_launch(void* const* d_in, const int* in_sizes, int n_in,
                              void* d_out, int out_size, void* d_ws, size_t ws_size,
                              hipStream_t stream) {
    const float* x    = (const float*)d_in[0];
    const float* Wih0 = (const float*)d_in[1];
    const float* Whh0 = (const float*)d_in[2];
    const float* bih0 = (const float*)d_in[3];
    const float* bhh0 = (const float*)d_in[4];
    const float* Wih1 = (const float*)d_in[5];
    const float* Whh1 = (const float*)d_in[6];
    const float* bih1 = (const float*)d_in[7];
    const float* bhh1 = (const float*)d_in[8];
    const float* Wfc  = (const float*)d_in[9];
    const float* bfc  = (const float*)d_in[10];
    float* out = (float*)d_out;

    const int B = in_sizes[0] / (TT * DD);   // 4096
    dim3 grid(B / NB), block(512);           // 256 blocks x 8 waves
    hipLaunchKernelGGL(lstm2_ks8, grid, block, 0, stream,
                       x, Wih0, Whh0, bih0, bhh0,
                       Wih1, Whh1, bih1, bhh1, Wfc, bfc, out);
}